// Round 18
// baseline (893.813 us; speedup 1.0000x reference)
//
// MultiheadSelectiveAttentionWithTokenPruning — MI355X round 18
// (r17 base; evict rewritten as PAIRED steps: one barrier exchange per TWO
//  evictions via exact per-wave (top1(step i), top2(step i+1)) packs.
//  Exact lexicographic semantics preserved -> bit-identical schedule.)
//
// Pipeline (all on `stream`, graph-capture safe, no statics):
//  1  cast_x      : X fp32 -> Xhi/Xlo bf16 (split for bf16x3 GEMM)
//  2  cast_w x4   : W fp32 -> W^T bf16 (hi[+lo for Wq/Wk])
//  3  gemm_qkv    : ONE launch: Yq,Yk (split), Yv (plain). 768 blocks.
//  4  lnpack_all  : ONE launch: LN(Yq)->Qb+q0s, LN(Yk)->Kb+k0s, Yv->Vb.
//  5  s64_kernel  : S[b,n,m] = relu(q0s.k0s/8), 64x64 tiles (bit-identical)
//  6  p_kernel    : column partial sums of S rows 0..1023 (8 chunks)
//  7  FUSED       : evict (2 blocks, PAIRED 4-wave) ∥ flash part 1
//                   (512 blocks, q<1024: prune mask vacuous).
//  8  FUSED       : flash2 (q>=1024; 512 blocks) ∥ gemmO part 1 (128 blocks,
//                   Ob rows n<1024, final after launch 7).
//  9  gemmO part2 : row-blocks y in {8..15,24..31} (needs flash2's Ob rows).
//
// PAIRED EVICT CORRECTNESS: per pair (i,i+1):
//   a  = wave top-1 of cum            (exact step-i argmax input)
//   cum += S[row i]                   (same per-slot add order as before)
//   (B,S) = wave top-2 of cum         (step-i+1 values; w1 excluded at
//                                      resolution, not by poison -> same set)
//   ONE barrier; resolution in all lanes:
//     w1 = max(a0..a3); cand_w = (B_w.lo==w1.lo ? S_w : B_w); w2 = max(cand)
//   (slots are wave-partitioned so only w1's wave can collide; top-2 merge is
//    associative over multisets; packs unique: lo=2048-m -> first-max ties)
//   poison w1,w2 (evti=i, i+1); cum += S[row i+1]   (-inf sticks)
//
// ws overlays: Ob reuses Xhi slot; S reuses Yq+Yk slots. Peak ws ~107.1 MB.

#include <hip/hip_runtime.h>

#define B_    2
#define N_    2048
#define D_    1024
#define H_    16
#define DH_   64
#define M_    2048
#define ROWS_ 4096
#define BUD_  1024

typedef unsigned short u16;
typedef unsigned int   u32;
typedef unsigned long long u64;
typedef __attribute__((ext_vector_type(8))) short short8;
typedef __attribute__((ext_vector_type(4))) float floatx4;

__device__ __forceinline__ u16 f2b(float f) {
    u32 u = __float_as_uint(f);
    return (u16)((u + 0x7FFFu + ((u >> 16) & 1u)) >> 16);   // RNE
}
__device__ __forceinline__ float b2f(u16 h) {
    return __uint_as_float(((u32)h) << 16);
}

// ---------------------------------------------------------------- cast X
__global__ __launch_bounds__(256) void cast_x_kernel(
    const float* __restrict__ X, u16* __restrict__ Xhi, u16* __restrict__ Xlo)
{
    int idx = (blockIdx.x * 256 + threadIdx.x) * 4;
    float4 v = *(const float4*)&X[idx];
    u16 h0 = f2b(v.x), h1 = f2b(v.y), h2 = f2b(v.z), h3 = f2b(v.w);
    ushort4 hv; hv.x = h0; hv.y = h1; hv.z = h2; hv.w = h3;
    *(ushort4*)&Xhi[idx] = hv;
    ushort4 lv;
    lv.x = f2b(v.x - b2f(h0)); lv.y = f2b(v.y - b2f(h1));
    lv.z = f2b(v.z - b2f(h2)); lv.w = f2b(v.w - b2f(h3));
    *(ushort4*)&Xlo[idx] = lv;
}

// ------------------------------------------------- cast + transpose W
__global__ __launch_bounds__(1024) void cast_w_kernel(
    const float* __restrict__ W, u16* __restrict__ Whi, u16* __restrict__ Wlo,
    int do_lo)
{
    __shared__ float tile[32][33];
    int tx = threadIdx.x, ty = threadIdx.y;
    int x = blockIdx.x * 32 + tx, y = blockIdx.y * 32 + ty;
    tile[ty][tx] = W[(size_t)y * D_ + x];
    __syncthreads();
    float v = tile[tx][ty];
    int n = blockIdx.x * 32 + ty, k = blockIdx.y * 32 + tx;
    u16 h = f2b(v);
    Whi[(size_t)n * D_ + k] = h;
    if (do_lo) Wlo[(size_t)n * D_ + k] = f2b(v - b2f(h));
}

// ------------------------------------------------------------- GEMM core
// C[row][col] = A[4096][1024] @ Bt^T  (Bt stored [n][k]); tile 128x128.
// MODE 1: C = Ah*Bh + Ah*Bl + Al*Bh  (bf16x3 split, ~fp32 precision)
template<int MODE>
__device__ void gemm_core(
    const u16* __restrict__ Ah, const u16* __restrict__ Al,
    const u16* __restrict__ Bh, const u16* __restrict__ Bl,
    float* __restrict__ C, int bx, int m0)
{
    __shared__ __align__(16) u16 sAh[128 * 32];
    __shared__ __align__(16) u16 sBh[128 * 32];
    __shared__ __align__(16) u16 sAl[MODE ? 128 * 32 : 8];
    __shared__ __align__(16) u16 sBl[MODE ? 128 * 32 : 8];
    int tid = threadIdx.x;
    int lane = tid & 63, wv = tid >> 6;
    int wr = wv >> 1, wc = wv & 1;
    int quad = lane >> 4, l16 = lane & 15;
    int n0 = bx * 128;

    floatx4 acc[4][4];
    floatx4 zero = {0.f, 0.f, 0.f, 0.f};
#pragma unroll
    for (int i = 0; i < 4; ++i)
#pragma unroll
        for (int j = 0; j < 4; ++j) acc[i][j] = zero;

    for (int k0 = 0; k0 < 1024; k0 += 32) {
#pragma unroll
        for (int it = 0; it < 2; ++it) {
            int e = (tid + it * 256) * 8;
            int r = e >> 5, c = e & 31;
            *(uint4*)&sAh[e] = *(const uint4*)&Ah[(size_t)(m0 + r) * 1024 + k0 + c];
            *(uint4*)&sBh[e] = *(const uint4*)&Bh[(size_t)(n0 + r) * 1024 + k0 + c];
            if (MODE) {
                *(uint4*)&sAl[e] = *(const uint4*)&Al[(size_t)(m0 + r) * 1024 + k0 + c];
                *(uint4*)&sBl[e] = *(const uint4*)&Bl[(size_t)(n0 + r) * 1024 + k0 + c];
            }
        }
        __syncthreads();
        short8 ah[4], al[4], bh[4], bl[4];
#pragma unroll
        for (int x = 0; x < 4; ++x) {
            int ra = (wr * 64 + x * 16 + l16) * 32 + quad * 8;
            int rb = (wc * 64 + x * 16 + l16) * 32 + quad * 8;
            ah[x] = *(const short8*)&sAh[ra];
            bh[x] = *(const short8*)&sBh[rb];
            if (MODE) {
                al[x] = *(const short8*)&sAl[ra];
                bl[x] = *(const short8*)&sBl[rb];
            }
        }
#pragma unroll
        for (int mi = 0; mi < 4; ++mi)
#pragma unroll
            for (int ni = 0; ni < 4; ++ni) {
                acc[mi][ni] = __builtin_amdgcn_mfma_f32_16x16x32_bf16(
                    ah[mi], bh[ni], acc[mi][ni], 0, 0, 0);
                if (MODE) {
                    acc[mi][ni] = __builtin_amdgcn_mfma_f32_16x16x32_bf16(
                        ah[mi], bl[ni], acc[mi][ni], 0, 0, 0);
                    acc[mi][ni] = __builtin_amdgcn_mfma_f32_16x16x32_bf16(
                        al[mi], bh[ni], acc[mi][ni], 0, 0, 0);
                }
            }
        __syncthreads();
    }
    // C/D layout: col = lane&15, row = (lane>>4)*4 + reg   [verified m89/m91]
#pragma unroll
    for (int mi = 0; mi < 4; ++mi)
#pragma unroll
        for (int ni = 0; ni < 4; ++ni)
#pragma unroll
            for (int r = 0; r < 4; ++r) {
                int row = m0 + wr * 64 + mi * 16 + quad * 4 + r;
                int col = n0 + wc * 64 + ni * 16 + l16;
                C[(size_t)row * 1024 + col] = acc[mi][ni][r];
            }
}

// ------------------- ONE launch for all three QKV gemms (z selects)
__global__ __launch_bounds__(256) void gemm_qkv_kernel(
    const u16* __restrict__ Xhi, const u16* __restrict__ Xlo,
    const u16* __restrict__ Wqh, const u16* __restrict__ Wql,
    const u16* __restrict__ Wkh, const u16* __restrict__ Wkl,
    const u16* __restrict__ Wvh,
    float* __restrict__ Yq, float* __restrict__ Yk, float* __restrict__ Yv)
{
    int m0 = blockIdx.y * 128;
    if (blockIdx.z == 0)
        gemm_core<1>(Xhi, Xlo, Wqh, Wql, Yq, blockIdx.x, m0);
    else if (blockIdx.z == 1)
        gemm_core<1>(Xhi, Xlo, Wkh, Wkl, Yk, blockIdx.x, m0);
    else
        gemm_core<0>(Xhi, nullptr, Wvh, nullptr, Yv, blockIdx.x, m0);
}

// standalone gemm launch (gemmO part 2). ymode 2: y'<8 -> y'+8, else y'+16.
template<int MODE>
__global__ __launch_bounds__(256) void gemm_kernel_t(
    const u16* __restrict__ Ah, const u16* __restrict__ Al,
    const u16* __restrict__ Bh, const u16* __restrict__ Bl,
    float* __restrict__ C, int ymode)
{
    int by = blockIdx.y;
    int yidx = (ymode == 0) ? by : ((by < 8) ? by + 8 : by + 16);
    gemm_core<MODE>(Ah, Al, Bh, Bl, C, blockIdx.x, yidx * 128);
}

// ------------------------------- LayerNorm + pack (ONE launch, y selects)
__global__ __launch_bounds__(256) void lnpack_all_kernel(
    const float* __restrict__ Yq, const float* __restrict__ Yk,
    const float* __restrict__ Yv,
    const float* __restrict__ gq, const float* __restrict__ bq,
    const float* __restrict__ gk, const float* __restrict__ bk,
    u16* __restrict__ Qb, u16* __restrict__ Kb, u16* __restrict__ Vb,
    float* __restrict__ q0s, float* __restrict__ k0s)
{
    const float* Y; const float* gamma; const float* beta;
    u16* Pk; float* head0; int do_ln;
    if (blockIdx.y == 0) { Y = Yq; gamma = gq; beta = bq; Pk = Qb; head0 = q0s; do_ln = 1; }
    else if (blockIdx.y == 1) { Y = Yk; gamma = gk; beta = bk; Pk = Kb; head0 = k0s; do_ln = 1; }
    else { Y = Yv; gamma = nullptr; beta = nullptr; Pk = Vb; head0 = nullptr; do_ln = 0; }

    int r = blockIdx.x;
    int tid = threadIdx.x;
    float4 v = *(const float4*)&Y[(size_t)r * D_ + tid * 4];
    float mu = 0.f, rsig = 1.f;
    __shared__ float sS[4], sQ[4];
    if (do_ln) {
        float s = v.x + v.y + v.z + v.w;
        float q = v.x * v.x + v.y * v.y + v.z * v.z + v.w * v.w;
#pragma unroll
        for (int d = 1; d < 64; d <<= 1) { s += __shfl_xor(s, d); q += __shfl_xor(q, d); }
        if ((tid & 63) == 0) { sS[tid >> 6] = s; sQ[tid >> 6] = q; }
        __syncthreads();
        s = sS[0] + sS[1] + sS[2] + sS[3];
        q = sQ[0] + sQ[1] + sQ[2] + sQ[3];
        mu = s * (1.f / 1024.f);
        float var = q * (1.f / 1024.f) - mu * mu;
        rsig = rsqrtf(var + 1e-5f);
    }
    int b = r >> 11, n = r & 2047;
    float xs[4] = {v.x, v.y, v.z, v.w};
#pragma unroll
    for (int j = 0; j < 4; ++j) {
        int c = tid * 4 + j;
        float val = do_ln ? ((xs[j] - mu) * rsig * gamma[c] + beta[c]) : xs[j];
        int h = c >> 6, dh = c & 63;
        Pk[(((size_t)b * H_ + h) * N_ + n) * DH_ + dh] = f2b(val);
        if (head0 && c < 64) head0[(size_t)r * 64 + c] = val;
    }
}

// ------------------------------------- head-0 selection scores S (64x64)
__global__ __launch_bounds__(256) void s64_kernel(
    const float* __restrict__ q0, const float* __restrict__ k0,
    float* __restrict__ S)
{
    int b = blockIdx.z;
    int n0 = blockIdx.y * 64, m0 = blockIdx.x * 64;
    int tid = threadIdx.x;
    int tx = tid & 15, ty = tid >> 4;
    floatx4 zero = {0.f, 0.f, 0.f, 0.f};
    if (m0 > n0 + 63) {                 // fully above diagonal -> zeros
#pragma unroll
        for (int i = 0; i < 4; ++i) {
            int n = n0 + 4 * ty + i;
            *(floatx4*)&S[((size_t)b * N_ + n) * M_ + m0 + 4 * tx] = zero;
        }
        return;
    }
    __shared__ float sq[64][65], sk[64][65];
    {
        int r = tid >> 2, cseg = (tid & 3) * 16;
        const float* qrow = &q0[((size_t)b * N_ + n0 + r) * 64 + cseg];
        const float* krow = &k0[((size_t)b * N_ + m0 + r) * 64 + cseg];
#pragma unroll
        for (int u = 0; u < 4; ++u) {
            float4 qa = *(const float4*)&qrow[u * 4];
            sq[r][cseg + u * 4 + 0] = qa.x; sq[r][cseg + u * 4 + 1] = qa.y;
            sq[r][cseg + u * 4 + 2] = qa.z; sq[r][cseg + u * 4 + 3] = qa.w;
            float4 ka = *(const float4*)&krow[u * 4];
            sk[r][cseg + u * 4 + 0] = ka.x; sk[r][cseg + u * 4 + 1] = ka.y;
            sk[r][cseg + u * 4 + 2] = ka.z; sk[r][cseg + u * 4 + 3] = ka.w;
        }
    }
    __syncthreads();
    float acc[4][4];
#pragma unroll
    for (int i = 0; i < 4; ++i)
#pragma unroll
        for (int j = 0; j < 4; ++j) acc[i][j] = 0.f;
#pragma unroll 8
    for (int d = 0; d < 64; ++d) {
        float qv[4], kv[4];
#pragma unroll
        for (int i = 0; i < 4; ++i) qv[i] = sq[4 * ty + i][d];
#pragma unroll
        for (int j = 0; j < 4; ++j) kv[j] = sk[4 * tx + j][d];
#pragma unroll
        for (int i = 0; i < 4; ++i)
#pragma unroll
            for (int j = 0; j < 4; ++j) acc[i][j] += qv[i] * kv[j];
    }
#pragma unroll
    for (int i = 0; i < 4; ++i) {
        int n = n0 + 4 * ty + i;
        floatx4 out;
#pragma unroll
        for (int j = 0; j < 4; ++j) {
            int m = m0 + 4 * tx + j;
            out[j] = (m < n && m != 0) ? fmaxf(acc[i][j] * 0.125f, 0.f) : 0.f;
        }
        *(floatx4*)&S[((size_t)b * N_ + n) * M_ + m0 + 4 * tx] = out;
    }
}

// -------------------------------- partial column sums of S rows 0..1023
__global__ __launch_bounds__(256) void p_kernel(const float* __restrict__ S,
                                                float* __restrict__ P)
{
    int b = blockIdx.z, c = blockIdx.y;
    int m = blockIdx.x * 256 + threadIdx.x;
    const float* base = S + ((size_t)b * N_ + c * 128) * M_ + m;
    float s = 0.f;
    for (int j = 0; j < 128; ++j) s += base[(size_t)j * M_];
    P[((size_t)b * 8 + c) * M_ + m] = s;
}

// --------------------------------------------- sequential greedy eviction
// PAIRED: one barrier exchange per two evictions (see header comment).
__device__ __forceinline__ long long maxll(long long a, long long b) {
    return a > b ? a : b;
}
__device__ __forceinline__ long long mkpack(float v, u32 lo) {
    return (long long)((((u64)(u32)__float_as_int(v)) << 32) | (u64)lo);
}
template<int CTRL, int RMASK>
__device__ __forceinline__ long long dpp_ll(long long p) {
    int hi = (int)((u64)p >> 32), lo = (int)(u32)(u64)p;
    int ho = __builtin_amdgcn_update_dpp(hi, hi, CTRL, RMASK, 0xF, false);
    int lo2 = __builtin_amdgcn_update_dpp(lo, lo, CTRL, RMASK, 0xF, false);
    return (long long)((((u64)(u32)ho) << 32) | (u32)lo2);
}
template<int CTRL, int RMASK>
__device__ __forceinline__ void dpp_t1(long long& B) {
    B = maxll(B, dpp_ll<CTRL, RMASK>(B));
}
template<int CTRL, int RMASK>
__device__ __forceinline__ void dpp_t2(long long& B, long long& S) {
    long long Bo = dpp_ll<CTRL, RMASK>(B);
    long long So = dpp_ll<CTRL, RMASK>(S);
    bool gt = Bo > B;
    long long nS = gt ? maxll(B, So) : maxll(S, Bo);
    B = gt ? Bo : B;
    S = nS;
}
// chains validated r3-r17: ror1/2/4/8 (full rows) + bcast15(0xA) + bcast31(0xC)
__device__ __forceinline__ long long wave_t1_63(long long B) {
    dpp_t1<0x121, 0xF>(B); dpp_t1<0x122, 0xF>(B); dpp_t1<0x124, 0xF>(B);
    dpp_t1<0x128, 0xF>(B); dpp_t1<0x142, 0xA>(B); dpp_t1<0x143, 0xC>(B);
    return B;
}
__device__ __forceinline__ void wave_t2_63(long long& B, long long& S) {
    dpp_t2<0x121, 0xF>(B, S); dpp_t2<0x122, 0xF>(B, S); dpp_t2<0x124, 0xF>(B, S);
    dpp_t2<0x128, 0xF>(B, S); dpp_t2<0x142, 0xA>(B, S); dpp_t2<0x143, 0xC>(B, S);
}

#define GLOAD(dst, voff, ptr, imm)                                    \
    asm volatile("global_load_dwordx4 %0, %1, %2 offset:" #imm        \
                 : "=v"(dst) : "v"(voff), "s"(ptr) : "memory")

#define ISSUE2(bank, row)                                             \
    {                                                                 \
        u32 r_ = (u32)((row) < 2047 ? (row) : 2047);                  \
        u32 vo = wbyte + r_ * 8192u;                                  \
        GLOAD(bank[0], vo, Sb, 0);                                    \
        GLOAD(bank[1], vo, Sb, 1024);                                 \
    }

#define VWAIT4()                                                      \
    do { asm volatile("s_waitcnt vmcnt(4)" ::: "memory");             \
         __builtin_amdgcn_sched_barrier(0); } while (0)
#define VWAIT0()                                                      \
    do { asm volatile("s_waitcnt vmcnt(0)" ::: "memory");             \
         __builtin_amdgcn_sched_barrier(0); } while (0)

__device__ __forceinline__ long long pk2(uint2 q) {
    return (long long)((((u64)q.y) << 32) | q.x);
}

__device__ __forceinline__ void evict_pair(
    int i, int t, int w, int par,
    const u32 (&lov)[2][4], float (&cum)[2][4], int (&evti)[2][4],
    const floatx4 (&bi)[2], const floatx4 (&bi1)[2],
    uint2 (*spair)[4][3])
{
    const float NEGINF = __uint_as_float(0xFF800000u);
    // ---- top-1 over cum (exact step-i values); packs unique -> order-free
    long long a = mkpack(cum[0][0], lov[0][0]);
    a = maxll(a, mkpack(cum[0][1], lov[0][1]));
    a = maxll(a, mkpack(cum[0][2], lov[0][2]));
    a = maxll(a, mkpack(cum[0][3], lov[0][3]));
    a = maxll(a, mkpack(cum[1][0], lov[1][0]));
    a = maxll(a, mkpack(cum[1][1], lov[1][1]));
    a = maxll(a, mkpack(cum[1][2], lov[1][2]));
    a = maxll(a, mkpack(cum[1][3], lov[1][3]));
    a = wave_t1_63(a);
    // ---- cum += S[row i]  (same per-slot order as sequential version)
#pragma unroll
    for (int c = 0; c < 2; ++c) {
        cum[c][0] += bi[c][0]; cum[c][1] += bi[c][1];
        cum[c][2] += bi[c][2]; cum[c][3] += bi[c][3];
    }
    // ---- per-lane top-2 of updated cum (step-i+1 values, pre-exclusion)
    long long Bst = mkpack(cum[0][0], lov[0][0]);
    long long Snd = (long long)0x8000000000000000ULL;
#define INS_(cc, ee)                                                   \
    { long long q_ = mkpack(cum[cc][ee], lov[cc][ee]);                 \
      bool gt_ = q_ > Bst;                                             \
      Snd = gt_ ? Bst : maxll(Snd, q_);                                \
      Bst = gt_ ? q_ : Bst; }
    INS_(0, 1) INS_(0, 2) INS_(0, 3)
    INS_(1, 0) INS_(1, 1) INS_(1, 2) INS_(1, 3)
#undef INS_
    wave_t2_63(Bst, Snd);
    // ---- ONE exchange for both steps
    if (t == 63) {
        spair[par][w][0] = make_uint2((u32)(u64)a,   (u32)((u64)a >> 32));
        spair[par][w][1] = make_uint2((u32)(u64)Bst, (u32)((u64)Bst >> 32));
        spair[par][w][2] = make_uint2((u32)(u64)Snd, (u32)((u64)Snd >> 32));
    }
    asm volatile("s_waitcnt lgkmcnt(0)" ::: "memory");
    __builtin_amdgcn_sched_barrier(0);
    __builtin_amdgcn_s_barrier();      // raw barrier: no vmcnt drain
    __builtin_amdgcn_sched_barrier(0);
    long long A0 = pk2(spair[par][0][0]), A1 = pk2(spair[par][1][0]);
    long long A2 = pk2(spair[par][2][0]), A3 = pk2(spair[par][3][0]);
    long long B0 = pk2(spair[par][0][1]), B1 = pk2(spair[par][1][1]);
    long long B2 = pk2(spair[par][2][1]), B3 = pk2(spair[par][3][1]);
    long long S0 = pk2(spair[par][0][2]), S1 = pk2(spair[par][1][2]);
    long long S2 = pk2(spair[par][2][2]), S3 = pk2(spair[par][3][2]);
    const long long w1 = maxll(maxll(A0, A1), maxll(A2, A3));
    const u32 w1lo = (u32)(u64)w1;
    // per-wave step-i+1 candidate: exclude w1's slot (only its owner wave
    // can hold it; slots are wave-partitioned)
    long long C0 = ((u32)(u64)B0 == w1lo) ? S0 : B0;
    long long C1 = ((u32)(u64)B1 == w1lo) ? S1 : B1;
    long long C2 = ((u32)(u64)B2 == w1lo) ? S2 : B2;
    long long C3 = ((u32)(u64)B3 == w1lo) ? S3 : B3;
    const long long w2 = maxll(maxll(C0, C1), maxll(C2, C3));
    const u32 w2lo = (u32)(u64)w2;
    // ---- poison + record both evictions, then add S[row i+1] (-inf sticks)
#pragma unroll
    for (int c = 0; c < 2; ++c)
#pragma unroll
        for (int e = 0; e < 4; ++e) {
            bool h1 = (lov[c][e] == w1lo);
            bool h2 = (lov[c][e] == w2lo);
            cum[c][e] = (h1 || h2) ? NEGINF : cum[c][e];
            evti[c][e] = h1 ? i : (h2 ? (i + 1) : evti[c][e]);
        }
#pragma unroll
    for (int c = 0; c < 2; ++c) {
        cum[c][0] += bi1[c][0]; cum[c][1] += bi1[c][1];
        cum[c][2] += bi1[c][2]; cum[c][3] += bi1[c][3];
    }
}

__device__ void evict_role(const float* __restrict__ S,
                           const float* __restrict__ P,
                           int* __restrict__ evt)
{
    int b = blockIdx.x;
    int tid = threadIdx.x;
    int w = tid >> 6, t = tid & 63;            // 4 waves
    const float* Sb = S + (size_t)b * N_ * M_;
    int* evtb = evt + b * M_;
    const int mbase = 512 * w + 4 * t;
    const u32 wbyte = (u32)(2048 * w + 16 * t);  // byte offset within a row
    __shared__ uint2 spair[2][4][3];            // [parity][wave][a,B,S]
    u32 lov[2][4];
    int evti[2][4];
#pragma unroll
    for (int c = 0; c < 2; ++c)
#pragma unroll
        for (int e = 0; e < 4; ++e) {
            lov[c][e] = (u32)(2048 - (mbase + 256 * c + e));
            evti[c][e] = 0x3FFFFFFF;
        }
    // initial cum = column sums of the 8 partial chunks (same per-slot add
    // order as rounds 0-17 -> bitwise identical trajectories)
    float cum[2][4];
#pragma unroll
    for (int c = 0; c < 2; ++c) {
        float ax = 0.f, ay = 0.f, az = 0.f, aw = 0.f;
#pragma unroll
        for (int cc = 0; cc < 8; ++cc) {
            floatx4 pv = *(const floatx4*)&P[((size_t)b * 8 + cc) * M_ + mbase + 256 * c];
            ax += pv[0]; ay += pv[1]; az += pv[2]; aw += pv[3];
        }
        cum[c][0] = ax; cum[c][1] = ay; cum[c][2] = az; cum[c][3] = aw;
    }
    // fence: drain compiler-tracked loads so asm vmcnt counting is exact
    VWAIT0();
    floatx4 bA[2], bB[2], bC[2], bD[2];
    ISSUE2(bA, 1024)
    ISSUE2(bB, 1025)
    ISSUE2(bC, 1026)
    ISSUE2(bD, 1027)
#pragma unroll 1
    for (int ip = 1024; ip < 2048; ip += 4) {
        VWAIT4();                                   // banks A,B ready
        evict_pair(ip + 0, t, w, 0, lov, cum, evti, bA, bB, spair);
        ISSUE2(bA, ip + 4)
        ISSUE2(bB, ip + 5)
        VWAIT4();                                   // banks C,D ready
        evict_pair(ip + 2, t, w, 1, lov, cum, evti, bC, bD, spair);
        ISSUE2(bC, ip + 6)
        ISSUE2(bD, ip + 7)
    }
    VWAIT0();   // drain leftover bank loads before reusing the vmem queue
    // single coalesced write pass (the only global stores in this role)
#pragma unroll
    for (int c = 0; c < 2; ++c) {
        int4 o; o.x = evti[c][0]; o.y = evti[c][1];
        o.z = evti[c][2]; o.w = evti[c][3];
        *(int4*)&evtb[mbase + 256 * c] = o;
    }
}

// ------------------------------------------------------ flash attention
// role shared by fused launches (evtg==nullptr: q<1024, mask pure causal).
__device__ void flash_role(
    const u16* __restrict__ Qb, const u16* __restrict__ Kb,
    const u16* __restrict__ Vb, const int* __restrict__ evtg,
    u16* __restrict__ Ob, int bh, int q0, int ktiles)
{
    int b = bh >> 4, h = bh & 15;
    int tid = threadIdx.x, lane = tid & 63, w = tid >> 6;
    int quad = lane >> 4, l16 = lane & 15;
    const u16* Qh = Qb + (size_t)bh * N_ * DH_;
    const u16* Kh = Kb + (size_t)bh * N_ * DH_;
    const u16* Vh = Vb + (size_t)bh * N_ * DH_;
    __shared__ __align__(16) u16 sK[64 * 64];
    __shared__ __align__(16) u16 sV[64 * 64];     // transposed [dh][key]
    __shared__ __align__(16) u16 sP[4][16 * 64];  // wave-private P
    __shared__ int sevt[64];

    // Q A-frags in registers: A[m=lane&15][k=quad*8+j]
    short8 aq0 = *(const short8*)&Qh[(size_t)(q0 + w * 16 + l16) * 64 + quad * 8];
    short8 aq1 = *(const short8*)&Qh[(size_t)(q0 + w * 16 + l16) * 64 + quad * 8 + 32];

    floatx4 zero = {0.f, 0.f, 0.f, 0.f};
    floatx4 accO[4];
#pragma unroll
    for (int d = 0; d < 4; ++d) accO[d] = zero;
    float m_i[4] = {-1e30f, -1e30f, -1e30f, -1e30f};
    float l_i[4] = {0.f, 0.f, 0.f, 0.f};

    for (int kt = 0; kt < ktiles; ++kt) {
        int k0 = kt * 64;
#pragma unroll
        for (int it = 0; it < 2; ++it) {
            int e = (tid + it * 256) * 8;
            int r = e >> 6, c = e & 63;
            *(uint4*)&sK[e] = *(const uint4*)&Kh[(size_t)(k0 + r) * 64 + c];
            uint4 vv = *(const uint4*)&Vh[(size_t)(k0 + r) * 64 + c];
            sV[(c + 0) * 64 + r] = (u16)(vv.x & 0xFFFF);
            sV[(c + 1) * 64 + r] = (u16)(vv.x >> 16);
            sV[(c + 2) * 64 + r] = (u16)(vv.y & 0xFFFF);
            sV[(c + 3) * 64 + r] = (u16)(vv.y >> 16);
            sV[(c + 4) * 64 + r] = (u16)(vv.z & 0xFFFF);
            sV[(c + 5) * 64 + r] = (u16)(vv.z >> 16);
            sV[(c + 6) * 64 + r] = (u16)(vv.w & 0xFFFF);
            sV[(c + 7) * 64 + r] = (u16)(vv.w >> 16);
        }
        if (evtg && tid < 64) sevt[tid] = evtg[b * M_ + k0 + tid];
        __syncthreads();

        floatx4 lg[4];
        int nbase = q0 + w * 16 + quad * 4;
#pragma unroll
        for (int s = 0; s < 4; ++s) {
            floatx4 sc = zero;
            short8 bk0 = *(const short8*)&sK[(s * 16 + l16) * 64 + quad * 8];
            short8 bk1 = *(const short8*)&sK[(s * 16 + l16) * 64 + quad * 8 + 32];
            sc = __builtin_amdgcn_mfma_f32_16x16x32_bf16(aq0, bk0, sc, 0, 0, 0);
            sc = __builtin_amdgcn_mfma_f32_16x16x32_bf16(aq1, bk1, sc, 0, 0, 0);
            int m = k0 + s * 16 + l16;
            int ev = evtg ? sevt[s * 16 + l16] : 0x7FFFFFFF;
#pragma unroll
            for (int r = 0; r < 4; ++r) {
                int n = nbase + r;
                bool keep = (m <= n) && (n < ev);
                lg[s][r] = keep ? sc[r] * 0.125f : -1e30f;
            }
        }
        float mnew[4], scale[4], rs[4];
#pragma unroll
        for (int r = 0; r < 4; ++r) {
            float mx = fmaxf(fmaxf(lg[0][r], lg[1][r]), fmaxf(lg[2][r], lg[3][r]));
#pragma unroll
            for (int d = 1; d < 16; d <<= 1) mx = fmaxf(mx, __shfl_xor(mx, d));
            mnew[r] = fmaxf(m_i[r], mx);
            scale[r] = __expf(m_i[r] - mnew[r]);
            m_i[r] = mnew[r];
            rs[r] = 0.f;
        }
#pragma unroll
        for (int s = 0; s < 4; ++s)
#pragma unroll
            for (int r = 0; r < 4; ++r) {
                float p = __expf(lg[s][r] - mnew[r]);
                rs[r] += p;
                sP[w][(quad * 4 + r) * 64 + s * 16 + l16] = f2b(p);
            }
#pragma unroll
        for (int r = 0; r < 4; ++r) {
            float t_ = rs[r];
#pragma unroll
            for (int d = 1; d < 16; d <<= 1) t_ += __shfl_xor(t_, d);
            l_i[r] = l_i[r] * scale[r] + t_;
        }
#pragma unroll
        for (int dd = 0; dd < 4; ++dd) {
            accO[dd][0] *= scale[0]; accO[dd][1] *= scale[1];
            accO[dd][2] *= scale[2]; accO[dd][3] *= scale[3];
        }
        // P: C-layout -> A-layout via wave-private LDS round-trip
        short8 ap0 = *(const short8*)&sP[w][l16 * 64 + quad * 8];
        short8 ap1 = *(const short8*)&sP[w][l16 * 64 + quad * 8 + 32];
#pragma unroll
        for (int dd = 0; dd < 4; ++dd) {
            short8 bv0 = *(const short8*)&sV[(dd * 16 + l16) * 64 + quad * 8];
            short8 bv1 = *(const short8*)&sV[(dd * 16 + l16) * 64 + quad * 8 + 32];
            accO[dd] = __builtin_amdgcn_mfma_f32_16x16x32_bf16(ap0, bv0, accO[dd], 0, 0, 0);
            accO[dd] = __builtin_amdgcn_mfma_f32_16x16x32_bf16(ap1, bv1, accO[dd], 0, 0, 0);
        }
        __syncthreads();
    }
#pragma unroll
    for (int dd = 0; dd < 4; ++dd)
#pragma unroll
        for (int r = 0; r < 4; ++r) {
            int n = q0 + w * 16 + quad * 4 + r;
            int col = h * 64 + dd * 16 + l16;
            Ob[((size_t)b * N_ + n) * D_ + col] = f2b(accO[dd][r] / l_i[r]);
        }
}

// --------------------------- fused launch: evict ∥ flash part 1 (q<1024)
__global__ __launch_bounds__(256) void fused_evict_flash1(
    const float* __restrict__ S, const float* __restrict__ P,
    int* __restrict__ evt,
    const u16* __restrict__ Qb, const u16* __restrict__ Kb,
    const u16* __restrict__ Vb, u16* __restrict__ Ob)
{
    if (blockIdx.x < 2) {
        evict_role(S, P, evt);
    } else {
        int fid = blockIdx.x - 2;          // 0..511
        int bh = fid >> 4, j = fid & 15;   // q-tiles 0..15: n < 1024, no evt
        flash_role(Qb, Kb, Vb, nullptr, Ob, bh, j * 64, j + 1);
    }
}

// ---------------- fused launch: flash part 2 (q>=1024) ∥ gemmO part 1
__global__ __launch_bounds__(256) void fused_flash2_gemmo1(
    const u16* __restrict__ Qb, const u16* __restrict__ Kb,
    const u16* __restrict__ Vb, const int* __restrict__ evt,
    u16* __restrict__ Ob, const u16* __restrict__ Woh,
    float* __restrict__ Out)
{
    if (blockIdx.x < 512) {
        int fid = blockIdx.x;
        int bh = fid >> 4, j = (fid & 15) + 16;   // q-tiles 16..31
        flash_role(Qb, Kb, Vb, evt, Ob, bh, j * 64, j + 1);
    } else {
        int gid = blockIdx.x - 512;               // 0..127
        int bx = gid & 7, gy = gid >> 3;          // gy 0..15
        int yidx = (gy < 8) ? gy : gy + 8;        // rows {0..7,16..23}
        gemm_core<0>((const u16*)Ob, nullptr, Woh, nullptr, Out, bx, yidx * 128);
    }
}

// ---------------------------------------------------------------- launch
extern "C" void kernel_launch(void* const* d_in, const int* in_sizes, int n_in,
                              void* d_out, int out_size, void* d_ws, size_t ws_size,
                              hipStream_t stream)
{
    (void)in_sizes; (void)n_in; (void)out_size; (void)ws_size;
    const float* X  = (const float*)d_in[0];
    const float* Wq = (const float*)d_in[1];
    const float* Wk = (const float*)d_in[2];
    const float* Wv = (const float*)d_in[3];
    const float* Wo = (const float*)d_in[4];
    const float* gq = (const float*)d_in[5];
    const float* bq = (const float*)d_in[6];
    const float* gk = (const float*)d_in[7];
    const float* bk = (const float*)d_in[8];
    // d_in[9] cache_k, d_in[10] cache_v, d_in[11] start_pos: start_pos==0 here.

    char* p = (char*)d_ws;
    const size_t SZ_XH = (size_t)ROWS_ * D_ * 2;   // 8 MiB bf16
    const size_t SZ_W  = (size_t)D_ * D_ * 2;      // 2 MiB bf16
    const size_t SZ_Y  = (size_t)ROWS_ * D_ * 4;   // 16 MiB fp32
    const size_t SZ_PK = (size_t)ROWS_ * D_ * 2;   // 8 MiB bf16
    const size_t SZ_H0 = (size_t)ROWS_ * 64 * 4;   // 1 MiB fp32

    size_t o = 0;
    u16* Xhi = (u16*)(p + o); o += SZ_XH;
    u16* Xlo = (u16*)(p + o); o += SZ_XH;
    u16* Wqh = (u16*)(p + o); o += SZ_W;
    u16* Wql = (u16*)(p + o); o += SZ_W;
    u16* Wkh = (u16*)(p + o); o += SZ_W;
    u16* Wkl = (u16*)(p + o); o += SZ_W;
    u16* Wvh = (u16*)(p + o); o += SZ_W;
    u16* Woh = (u16*)(p + o); o += SZ_W;
    float* Yq = (float*)(p + o); size_t oYq = o; o += SZ_Y;
    float* Yk = (float*)(p + o); o += SZ_Y;
    float* Yv = (float*)(p + o); o += SZ_Y;
    u16* Qb = (u16*)(p + o); o += SZ_PK;
    u16* Kb = (u16*)(p + o); o += SZ_PK;
    u16* Vb = (u16*)(p + o); o += SZ_PK;
    float* q0s = (float*)(p + o); o += SZ_H0;
    float* k0s = (float*)(p + o); o += SZ_H0;
    float* Pp  = (float*)(p + o); o += (size_t)B_ * 8 * M_ * 4;
    int* evt   = (int*)(p + o);  o += (size_t)B_ * M_ * 4;
    // overlays (dead slots):
    float* S = (float*)(p + oYq);   // 32 MiB over Yq+Yk, used after LN
    u16* Ob  = Xhi;                 // 8 MiB over Xhi, used after all X-GEMMs

    cast_x_kernel<<<ROWS_ * D_ / (256 * 4), 256, 0, stream>>>(X, Xhi, Xlo);
    dim3 wgrid(32, 32), wblk(32, 32);
    cast_w_kernel<<<wgrid, wblk, 0, stream>>>(Wq, Wqh, Wql, 1);
    cast_w_kernel<<<wgrid, wblk, 0, stream>>>(Wk, Wkh, Wkl, 1);
    cast_w_kernel<<<wgrid, wblk, 0, stream>>>(Wv, Wvh, nullptr, 0);
    cast_w_kernel<<<wgrid, wblk, 0, stream>>>(Wo, Woh, nullptr, 0);

    // all three QKV gemms in one launch (768 blocks, z selects)
    gemm_qkv_kernel<<<dim3(8, 32, 3), 256, 0, stream>>>(
        Xhi, Xlo, Wqh, Wql, Wkh, Wkl, Wvh, Yq, Yk, Yv);

    // all three lnpacks in one launch (y selects)
    lnpack_all_kernel<<<dim3(ROWS_, 3), 256, 0, stream>>>(
        Yq, Yk, Yv, gq, bq, gk, bk, Qb, Kb, Vb, q0s, k0s);

    s64_kernel<<<dim3(M_ / 64, N_ / 64, B_), 256, 0, stream>>>(q0s, k0s, S);
    p_kernel<<<dim3(M_ / 256, 8, B_), 256, 0, stream>>>(S, Pp);

    // evict (blocks 0,1) runs concurrently with flash q<1024 (blocks 2..513)
    fused_evict_flash1<<<514, 256, 0, stream>>>(S, Pp, evt, Qb, Kb, Vb, Ob);
    // flash q>=1024 (512 blocks) ∥ gemmO part 1 (128 blocks, Ob rows n<1024)
    fused_flash2_gemmo1<<<640, 256, 0, stream>>>(
        Qb, Kb, Vb, evt, Ob, Woh, (float*)d_out);
    // gemmO part 2 (rows n>=1024, needs flash2 output)
    gemm_kernel_t<0><<<dim3(8, 16), 256, 0, stream>>>(
        (const u16*)Ob, nullptr, Woh, nullptr, (float*)d_out, 2);
}